// Round 7
// baseline (101.059 us; speedup 1.0000x reference)
//
#include <hip/hip_runtime.h>
#include <stdint.h>

#define EMB    1024
#define NHEAD  16
#define HDIM   64
#define NSEQ   2048
#define NBATCH 2
#define WINDOW 128
#define MROWS  (NBATCH * NSEQ)   // 4096

typedef __attribute__((ext_vector_type(8))) short  bf16x8;
typedef __attribute__((ext_vector_type(4))) float  f32x4;
typedef __attribute__((ext_vector_type(4))) short  short4v;

__device__ __forceinline__ unsigned short f2bf(float f) {
  union { float f; uint32_t u; } c; c.f = f;
  uint32_t u = c.u;
  u += 0x7fffu + ((u >> 16) & 1u);   // round-to-nearest-even
  return (unsigned short)(u >> 16);
}

#define GLOAD16(g, l) __builtin_amdgcn_global_load_lds( \
    (const __attribute__((address_space(1))) void*)(g), \
    (__attribute__((address_space(3))) void*)(l), 16, 0, 0)

// ---------------- fp32 -> bf16 convert (x + 4 weights, one launch) ----------------
__global__ __launch_bounds__(256) void cvt_all(
    const float* __restrict__ x,
    const float* __restrict__ w0, const float* __restrict__ w1,
    const float* __restrict__ w2, const float* __restrict__ w3,
    unsigned short* __restrict__ xb,
    unsigned short* __restrict__ o0, unsigned short* __restrict__ o1,
    unsigned short* __restrict__ o2, unsigned short* __restrict__ o3) {
  const int i = blockIdx.x * 256 + threadIdx.x;   // float4 index
  const float* src; unsigned short* dst; int off;
  if (i < 1048576) { src = x; dst = xb; off = i; }
  else {
    int j = i - 1048576;
    int sel = j >> 18; off = j & 262143;
    src = sel == 0 ? w0 : sel == 1 ? w1 : sel == 2 ? w2 : w3;
    dst = sel == 0 ? o0 : sel == 1 ? o1 : sel == 2 ? o2 : o3;
  }
  float4 v = ((const float4*)src)[off];
  short4v o;
  o.x = (short)f2bf(v.x);
  o.y = (short)f2bf(v.y);
  o.z = (short)f2bf(v.z);
  o.w = (short)f2bf(v.w);
  ((short4v*)dst)[off] = o;
}

// ================= 256x256 8-wave QKV GEMM =================
// Block tile 256(M)x256(N), BK=64, 8 waves (2M x 4N), wave tile 128x64.
// 2 LDS slots x (A 32KB | B 32KB) = 128KB. Counted-vmcnt 2-ahead pipeline.
// ks=1 physical address = ks=0 physical ^ 64 (bit 6 of logical ks0 col is 0,
// swizzle XOR commutes) -- '+ 64' would carry into the row field for row&4.
__global__ __launch_bounds__(512, 2) void gemm_qkv(
    const unsigned short* __restrict__ A,
    const unsigned short* __restrict__ W0, const unsigned short* __restrict__ W1,
    const unsigned short* __restrict__ W2,
    const float* __restrict__ b0, const float* __restrict__ b1, const float* __restrict__ b2,
    unsigned short* __restrict__ O0, unsigned short* __restrict__ O1,
    unsigned short* __restrict__ O2) {
  constexpr int K = 1024, BK = 64, NT = K / BK;   // 16 K-tiles
  __shared__ char lds[2][65536];                   // 128KB: [slot][A 32KB | B 32KB]
  const int t    = threadIdx.x;                    // 0..511
  const int lane = t & 63;
  const int wv   = t >> 6;                         // 0..7
  const int lhi  = lane >> 4, llo = lane & 15;
  const int wr   = wv >> 2, wc = wv & 3;           // 2M x 4N wave grid

  // bijective XCD remap over 192 blocks (grid 16x4x3): tl = (orig%8)*24 + orig/8
  const int orig = blockIdx.x + 16 * blockIdx.y + 64 * blockIdx.z;
  const int tl   = (orig & 7) * 24 + (orig >> 3);
  const int bx   = tl / 12, rem = tl % 12, by = rem / 3, bz = rem % 3;
  const int m0   = bx * 256, n0 = by * 256;
  const unsigned short* Bw = bz == 0 ? W0 : bz == 1 ? W1 : W2;
  const float* bias        = bz == 0 ? b0 : bz == 1 ? b1 : b2;
  unsigned short* Cv       = bz == 0 ? (unsigned short*)O0
                           : bz == 1 ? (unsigned short*)O1 : (unsigned short*)O2;
  const int   mode  = (bz == 2) ? 1 : 0;           // 1 = V transposed
  const float scale = (bz == 0) ? 0.03125f : 1.0f; // fold 1/sqrt(EMB) into Q

  // staging: 8 gloads/thread/tile; li 0..3 -> A region, 4..7 -> B region.
  // linear LDS dest + inverse-swizzled global source (rule 21).
  const unsigned short* gsrc[8];
  int ldsoff[8];
  #pragma unroll
  for (int li = 0; li < 8; ++li) {
    const int isB = li >= 4;
    const int P = (li & 3) * 8192 + t * 16;        // byte within 32KB region
    const int L = P ^ (((P >> 7) & 7) << 4);
    const int row = L >> 7, sl = (L >> 4) & 7;     // row 0..255, 16B slot 0..7
    gsrc[li] = (isB ? Bw + (size_t)(n0 + row) * K : A + (size_t)(m0 + row) * K) + sl * 8;
    ldsoff[li] = isB * 32768 + (li & 3) * 8192 + wv * 1024;   // wave-uniform base
  }

  // fragment read byte-offsets (swizzled); ks=1 physical = ks=0 physical ^ 64
  int aoff[8], boff[4];
  #pragma unroll
  for (int mf = 0; mf < 8; ++mf) {
    const int ar = wr * 128 + mf * 16 + llo;
    aoff[mf] = (ar * 128 + lhi * 16) ^ ((ar & 7) << 4);
  }
  #pragma unroll
  for (int nf = 0; nf < 4; ++nf) {
    const int bc = wc * 64 + nf * 16 + llo;
    boff[nf] = 32768 + ((bc * 128 + lhi * 16) ^ ((bc & 7) << 4));
  }

  const f32x4 zero = {0.f, 0.f, 0.f, 0.f};
  f32x4 acc[8][4];
  #pragma unroll
  for (int i = 0; i < 8; ++i)
    #pragma unroll
    for (int j = 0; j < 4; ++j) acc[i][j] = zero;

  // prologue: stage tiles 0 and 1
  #pragma unroll
  for (int li = 0; li < 8; ++li) GLOAD16(gsrc[li], (char*)lds + ldsoff[li]);
  #pragma unroll
  for (int li = 0; li < 8; ++li) GLOAD16(gsrc[li] + BK, (char*)lds + 65536 + ldsoff[li]);

  for (int t0 = 0; t0 < NT; ++t0) {
    if (t0 + 1 < NT) asm volatile("s_waitcnt vmcnt(8)" ::: "memory");
    else             asm volatile("s_waitcnt vmcnt(0)" ::: "memory");
    asm volatile("s_barrier" ::: "memory");                 // tile t0 fully in LDS
    __builtin_amdgcn_sched_barrier(0);

    const char* base = (const char*)lds + (t0 & 1) * 65536;

    // ---- ks = 0 ----
    bf16x8 a0[8], bg0[4];
    #pragma unroll
    for (int mf = 0; mf < 8; ++mf) a0[mf] = *(const bf16x8*)(base + aoff[mf]);
    #pragma unroll
    for (int nf = 0; nf < 4; ++nf) bg0[nf] = *(const bf16x8*)(base + boff[nf]);
    __builtin_amdgcn_s_setprio(1);
    #pragma unroll
    for (int mf = 0; mf < 8; ++mf)
      #pragma unroll
      for (int nf = 0; nf < 4; ++nf)
        acc[mf][nf] = __builtin_amdgcn_mfma_f32_16x16x32_bf16(a0[mf], bg0[nf], acc[mf][nf], 0, 0, 0);
    __builtin_amdgcn_s_setprio(0);

    // ---- ks = 1 ----
    bf16x8 a1[8], bg1[4];
    #pragma unroll
    for (int mf = 0; mf < 8; ++mf) a1[mf] = *(const bf16x8*)(base + (aoff[mf] ^ 64));
    #pragma unroll
    for (int nf = 0; nf < 4; ++nf) bg1[nf] = *(const bf16x8*)(base + (boff[nf] ^ 64));
    asm volatile("s_waitcnt lgkmcnt(0)" ::: "memory");      // all my slot reads retired
    asm volatile("s_barrier" ::: "memory");                 // all waves done reading slot
    __builtin_amdgcn_sched_barrier(0);

    if (t0 + 2 < NT) {                                      // stage t0+2 into freed slot
      #pragma unroll
      for (int li = 0; li < 8; ++li)
        GLOAD16(gsrc[li] + (t0 + 2) * BK, (char*)lds + (t0 & 1) * 65536 + ldsoff[li]);
    }

    __builtin_amdgcn_s_setprio(1);
    #pragma unroll
    for (int mf = 0; mf < 8; ++mf)
      #pragma unroll
      for (int nf = 0; nf < 4; ++nf)
        acc[mf][nf] = __builtin_amdgcn_mfma_f32_16x16x32_bf16(a1[mf], bg1[nf], acc[mf][nf], 0, 0, 0);
    __builtin_amdgcn_s_setprio(0);
  }

  // ---- epilogue ----
  #pragma unroll
  for (int mf = 0; mf < 8; ++mf) {
    #pragma unroll
    for (int nf = 0; nf < 4; ++nf) {
      const int col = n0 + wc * 64 + nf * 16 + llo;
      if (mode == 1) {
        const int row_base = m0 + wr * 128 + mf * 16 + lhi * 4;
        const int bb = row_base >> 11, n = row_base & 2047;
        const int hh = col >> 6, dd = col & 63;
        short4v o;
        #pragma unroll
        for (int r = 0; r < 4; ++r) o[r] = (short)f2bf(acc[mf][nf][r] + bias[col]);
        unsigned short* p = Cv + ((size_t)((bb * NHEAD + hh) * HDIM + dd)) * NSEQ + n;
        *(short4v*)p = o;
      } else {
        #pragma unroll
        for (int r = 0; r < 4; ++r) {
          const int row = m0 + wr * 128 + mf * 16 + lhi * 4 + r;
          const float v = (acc[mf][nf][r] + bias[col]) * scale;
          const int bb = row >> 11, n = row & 2047;
          const int hh = col >> 6, dd = col & 63;
          Cv[((size_t)(bb * NHEAD + hh) * NSEQ + n) * HDIM + dd] = f2bf(v);
        }
      }
    }
  }
}

// ================= 128x128 4-wave GEMM (proj) =================
__device__ __forceinline__ void gemm_pipe128(const unsigned short* __restrict__ A,
                                             const unsigned short* __restrict__ Bw,
                                             const float* __restrict__ bias,
                                             float* __restrict__ Cv,
                                             int m0, int n0) {
  constexpr int K = 1024, BK = 64, NT = K / BK;
  __shared__ char lds[2][32768];
  const int t    = threadIdx.x;
  const int lane = t & 63;
  const int wv   = t >> 6;
  const int lhi  = lane >> 4, llo = lane & 15;
  const int wr   = wv >> 1, wc = wv & 1;

  const unsigned short* gsrc[8];
  int ldsoff[8];
  #pragma unroll
  for (int li = 0; li < 8; ++li) {
    const int isB = li >= 4;
    const int c = (isB ? (li - 4) : li) * 4 + wv;
    const int P = c * 1024 + lane * 16;
    const int L = P ^ (((P >> 7) & 7) << 4);
    const int row = L >> 7, sl = (L >> 4) & 7;
    gsrc[li] = (isB ? Bw + (size_t)(n0 + row) * K : A + (size_t)(m0 + row) * K) + sl * 8;
    ldsoff[li] = isB * 16384 + c * 1024;
  }

  int aoff[2][4], boff[2][4];
  #pragma unroll
  for (int ks = 0; ks < 2; ++ks)
    #pragma unroll
    for (int f = 0; f < 4; ++f) {
      const int ar = wr * 64 + f * 16 + llo;
      aoff[ks][f] = (ar * 128 + ks * 64 + lhi * 16) ^ ((ar & 7) << 4);
      const int bc = wc * 64 + f * 16 + llo;
      boff[ks][f] = 16384 + ((bc * 128 + ks * 64 + lhi * 16) ^ ((bc & 7) << 4));
    }

  const f32x4 zero = {0.f, 0.f, 0.f, 0.f};
  f32x4 acc[4][4];
  #pragma unroll
  for (int i = 0; i < 4; ++i)
    #pragma unroll
    for (int j = 0; j < 4; ++j) acc[i][j] = zero;

  #pragma unroll
  for (int li = 0; li < 8; ++li) GLOAD16(gsrc[li], (char*)lds + ldsoff[li]);
  #pragma unroll
  for (int li = 0; li < 8; ++li) GLOAD16(gsrc[li] + BK, (char*)lds + 32768 + ldsoff[li]);

  for (int t0 = 0; t0 < NT; ++t0) {
    if (t0 + 1 < NT) asm volatile("s_waitcnt vmcnt(8)" ::: "memory");
    else             asm volatile("s_waitcnt vmcnt(0)" ::: "memory");
    asm volatile("s_barrier" ::: "memory");
    __builtin_amdgcn_sched_barrier(0);

    const char* base = (const char*)lds + (t0 & 1) * 32768;
    bf16x8 af[2][4], bg[2][4];
    #pragma unroll
    for (int ks = 0; ks < 2; ++ks)
      #pragma unroll
      for (int f = 0; f < 4; ++f) {
        af[ks][f] = *(const bf16x8*)(base + aoff[ks][f]);
        bg[ks][f] = *(const bf16x8*)(base + boff[ks][f]);
      }
    asm volatile("s_waitcnt lgkmcnt(0)" ::: "memory");
    asm volatile("s_barrier" ::: "memory");
    __builtin_amdgcn_sched_barrier(0);

    if (t0 + 2 < NT) {
      #pragma unroll
      for (int li = 0; li < 8; ++li)
        GLOAD16(gsrc[li] + (t0 + 2) * BK, (char*)lds + (t0 & 1) * 32768 + ldsoff[li]);
    }

    __builtin_amdgcn_s_setprio(1);
    #pragma unroll
    for (int ks = 0; ks < 2; ++ks)
      #pragma unroll
      for (int mf = 0; mf < 4; ++mf)
        #pragma unroll
        for (int nf = 0; nf < 4; ++nf)
          acc[mf][nf] = __builtin_amdgcn_mfma_f32_16x16x32_bf16(af[ks][mf], bg[ks][nf], acc[mf][nf], 0, 0, 0);
    __builtin_amdgcn_s_setprio(0);
  }

  const int wm = wr * 64, wn = wc * 64;
  #pragma unroll
  for (int mf = 0; mf < 4; ++mf) {
    #pragma unroll
    for (int nf = 0; nf < 4; ++nf) {
      const int col = n0 + wn + nf * 16 + llo;
      #pragma unroll
      for (int r = 0; r < 4; ++r) {
        const int row = m0 + wm + mf * 16 + lhi * 4 + r;
        Cv[(size_t)row * EMB + col] = acc[mf][nf][r] + bias[col];
      }
    }
  }
}

__global__ __launch_bounds__(256, 2) void gemm_proj(
    const unsigned short* __restrict__ A, const unsigned short* __restrict__ W,
    const float* __restrict__ bias, float* __restrict__ O) {
  gemm_pipe128(A, W, bias, O, blockIdx.x * 128, blockIdx.y * 128);
}

// ---------------- windowed flash attention (fixed-max softmax) ----------------
// Layouts: Qh/Kh [B][H][N][64] bf16 (Q pre-scaled by 1/32); Vt [B][H][64][N] bf16.
__global__ __launch_bounds__(256) void attn_kernel(
    const unsigned short* __restrict__ Qh, const unsigned short* __restrict__ Kh,
    const unsigned short* __restrict__ Vt, unsigned short* __restrict__ AO) {
  __shared__ unsigned short P[4][16 * 32];
  const int t = threadIdx.x;
  const int lane = t & 63, wv = t >> 6;
  const int lhi = lane >> 4, llo = lane & 15;

  const int linear = blockIdx.x + 32 * (blockIdx.y + 16 * blockIdx.z);
  const int xcd = linear & 7, pos = linear >> 3;
  const int plane = xcd * 4 + (pos >> 5);
  const int qblk = pos & 31;
  const int b = plane >> 4, h = plane & 15;
  const int q0 = qblk * 64 + wv * 16;

  const size_t pbase = (size_t)plane * NSEQ * HDIM;

  bf16x8 aq0, aq1;
  {
    const unsigned short* qp = Qh + pbase + (size_t)(q0 + llo) * HDIM + 8 * lhi;
    aq0 = *(const bf16x8*)qp;
    aq1 = *(const bf16x8*)(qp + 32);
  }

  bf16x8 vones;
  #pragma unroll
  for (int j = 0; j < 8; ++j) vones[j] = (short)0x3F80;   // bf16 1.0

  const f32x4 zero = {0.f, 0.f, 0.f, 0.f};
  f32x4 accv[4];
  f32x4 s_acc = zero;
  #pragma unroll
  for (int i = 0; i < 4; ++i) accv[i] = zero;

  #pragma unroll 3
  for (int ct = 0; ct < 9; ++ct) {
    const int kb = q0 - WINDOW + ct * 32;
    f32x4 e[2];
    #pragma unroll
    for (int half = 0; half < 2; ++half) {
      int krow = kb + half * 16 + llo;
      int krc = krow < 0 ? 0 : (krow > NSEQ - 1 ? NSEQ - 1 : krow);
      const unsigned short* kp = Kh + pbase + (size_t)krc * HDIM + 8 * lhi;
      bf16x8 bk0 = *(const bf16x8*)kp;
      bf16x8 bk1 = *(const bf16x8*)(kp + 32);
      f32x4 z = zero;
      z = __builtin_amdgcn_mfma_f32_16x16x32_bf16(aq0, bk0, z, 0, 0, 0);
      z = __builtin_amdgcn_mfma_f32_16x16x32_bf16(aq1, bk1, z, 0, 0, 0);
      e[half] = z;
    }
    f32x4 p0, p1;
    #pragma unroll
    for (int half = 0; half < 2; ++half) {
      const int key = kb + half * 16 + llo;
      #pragma unroll
      for (int r = 0; r < 4; ++r) {
        const int q = q0 + lhi * 4 + r;
        const int dlt = key - q;
        const bool valid = (key >= 0) && (key < NSEQ) && (dlt <= WINDOW) && (dlt >= -WINDOW);
        const float ev = valid ? fminf(e[half][r], 40.f) : -1e30f;
        if (half == 0) p0[r] = __expf(ev); else p1[r] = __expf(ev);
      }
    }

    #pragma unroll
    for (int r = 0; r < 4; ++r) {
      P[wv][(lhi * 4 + r) * 32 + llo]      = f2bf(p0[r]);
      P[wv][(lhi * 4 + r) * 32 + 16 + llo] = f2bf(p1[r]);
    }
    const bf16x8 pa = *(const bf16x8*)&P[wv][llo * 32 + 8 * lhi];

    s_acc = __builtin_amdgcn_mfma_f32_16x16x32_bf16(pa, vones, s_acc, 0, 0, 0);

    {
      int c = kb + 8 * lhi;
      c = c < 0 ? 0 : (c > NSEQ - 8 ? NSEQ - 8 : c);
      #pragma unroll
      for (int fd = 0; fd < 4; ++fd) {
        const unsigned short* vp = Vt + pbase + (size_t)(fd * 16 + llo) * NSEQ + c;
        bf16x8 bv = *(const bf16x8*)vp;
        accv[fd] = __builtin_amdgcn_mfma_f32_16x16x32_bf16(pa, bv, accv[fd], 0, 0, 0);
      }
    }
  }

  #pragma unroll
  for (int fd = 0; fd < 4; ++fd) {
    #pragma unroll
    for (int r = 0; r < 4; ++r) {
      const float o = accv[fd][r] / s_acc[r];
      const int q = q0 + lhi * 4 + r;
      AO[((size_t)b * NSEQ + q) * EMB + h * HDIM + fd * 16 + llo] = f2bf(o);
    }
  }
}

// ---------------- launcher ----------------
extern "C" void kernel_launch(void* const* d_in, const int* in_sizes, int n_in,
                              void* d_out, int out_size, void* d_ws, size_t ws_size,
                              hipStream_t stream) {
  (void)in_sizes; (void)n_in; (void)out_size; (void)ws_size;
  const float* x  = (const float*)d_in[0];
  const float* Wq = (const float*)d_in[1];
  const float* bq = (const float*)d_in[2];
  const float* Wk = (const float*)d_in[3];
  const float* bk = (const float*)d_in[4];
  const float* Wv = (const float*)d_in[5];
  const float* bv = (const float*)d_in[6];
  const float* Wp = (const float*)d_in[7];
  const float* bp = (const float*)d_in[8];
  float* out = (float*)d_out;
  char* ws = (char*)d_ws;
  const size_t MB = 1u << 20;
  unsigned short* xb  = (unsigned short*)(ws + 0 * MB);
  unsigned short* Wqb = (unsigned short*)(ws + 8 * MB);
  unsigned short* Wkb = (unsigned short*)(ws + 10 * MB);
  unsigned short* Wvb = (unsigned short*)(ws + 12 * MB);
  unsigned short* Wpb = (unsigned short*)(ws + 14 * MB);
  unsigned short* Qb  = (unsigned short*)(ws + 16 * MB);
  unsigned short* Kb  = (unsigned short*)(ws + 24 * MB);
  unsigned short* Vtb = (unsigned short*)(ws + 32 * MB);
  unsigned short* AOb = (unsigned short*)(ws + 40 * MB);

  cvt_all<<<dim3(8192), dim3(256), 0, stream>>>(x, Wq, Wk, Wv, Wp,
                                                xb, Wqb, Wkb, Wvb, Wpb);

  gemm_qkv<<<dim3(MROWS / 256, EMB / 256, 3), dim3(512), 0, stream>>>(
      xb, Wqb, Wkb, Wvb, bq, bk, bv, Qb, Kb, Vtb);

  attn_kernel<<<dim3(NSEQ / 64, NHEAD, NBATCH), dim3(256), 0, stream>>>(Qb, Kb, Vtb, AOb);

  gemm_proj<<<dim3(MROWS / 128, EMB / 128), dim3(256), 0, stream>>>(AOb, Wpb, bp, out);
}